// Round 1
// baseline (2106.825 us; speedup 1.0000x reference)
//
#include <hip/hip_runtime.h>
#include <cmath>

#define NWG 256
#define TPB 256
#define HDIM 1024

static_assert(NWG * 4 == HDIM, "4 cells per WG");

// ---- relaxed agent-scope atomics: go to coherence point, never invalidate caches ----
__device__ __forceinline__ float ld_g(const float* p) {
  return __hip_atomic_load(p, __ATOMIC_RELAXED, __HIP_MEMORY_SCOPE_AGENT);
}
__device__ __forceinline__ void st_g(float* p, float v) {
  __hip_atomic_store(p, v, __ATOMIC_RELAXED, __HIP_MEMORY_SCOPE_AGENT);
}

__device__ __forceinline__ float wave_red64(float v) {
#pragma unroll
  for (int off = 32; off; off >>= 1) v += __shfl_xor(v, off, 64);
  return v;  // full sum in all 64 lanes
}

// dot of one 1024-wide weight row (global) with x (LDS), distributed over 64 lanes
__device__ __forceinline__ float dot1024(const float* __restrict__ w,
                                         const float* __restrict__ x, int lane) {
  const float4* w4 = reinterpret_cast<const float4*>(w);
  const float4* x4 = reinterpret_cast<const float4*>(x);
  float a0 = 0.f, a1 = 0.f;
#pragma unroll
  for (int k = 0; k < 4; k += 2) {
    float4 wa = w4[lane + 64 * k];
    float4 va = x4[lane + 64 * k];
    float4 wb = w4[lane + 64 * (k + 1)];
    float4 vb = x4[lane + 64 * (k + 1)];
    a0 = fmaf(wa.x, va.x, a0); a0 = fmaf(wa.y, va.y, a0);
    a0 = fmaf(wa.z, va.z, a0); a0 = fmaf(wa.w, va.w, a0);
    a1 = fmaf(wb.x, vb.x, a1); a1 = fmaf(wb.y, vb.y, a1);
    a1 = fmaf(wb.z, vb.z, a1); a1 = fmaf(wb.w, vb.w, a1);
  }
  return a0 + a1;
}

// 2-level sense-reversing grid barrier, relaxed atomics only (no cache invalidation).
// ws int layout: grp counters at int idx {0,16,...,112}, root at 128, sense at 144.
__device__ __forceinline__ void gbar(float* ws, int wg, int tid, int& lsense, int& fail) {
  __syncthreads();
  if (tid == 0) {
    int* ib = (int*)ws;
    int s = lsense ^ 1;
    lsense = s;
    asm volatile("s_waitcnt vmcnt(0)" ::: "memory");  // own h-stores are globally visible
    int old = __hip_atomic_fetch_add(&ib[(wg & 7) * 16], 1, __ATOMIC_RELAXED, __HIP_MEMORY_SCOPE_AGENT);
    bool set_sense = false;
    if (old == 31) {  // last of my 32-WG group
      int r = __hip_atomic_fetch_add(&ib[128], 1, __ATOMIC_RELAXED, __HIP_MEMORY_SCOPE_AGENT);
      if (r == 7) {   // last group overall: reset counters, then flip sense
#pragma unroll
        for (int g = 0; g < 8; ++g)
          __hip_atomic_store(&ib[g * 16], 0, __ATOMIC_RELAXED, __HIP_MEMORY_SCOPE_AGENT);
        __hip_atomic_store(&ib[128], 0, __ATOMIC_RELAXED, __HIP_MEMORY_SCOPE_AGENT);
        asm volatile("s_waitcnt vmcnt(0)" ::: "memory");  // resets visible before sense flip
        __hip_atomic_store(&ib[144], s, __ATOMIC_RELAXED, __HIP_MEMORY_SCOPE_AGENT);
        set_sense = true;
      }
    }
    if (!set_sense && !fail) {
      int spins = 0;
      while (__hip_atomic_load(&ib[144], __ATOMIC_RELAXED, __HIP_MEMORY_SCOPE_AGENT) != s) {
        if (++spins > (1 << 22)) { fail = 1; break; }  // anti-hang safeguard
        __builtin_amdgcn_s_sleep(1);
      }
    }
    asm volatile("" ::: "memory");
  }
  __syncthreads();
}

__device__ __forceinline__ void load_vec(float* dst, const float* src, int tid) {
#pragma unroll
  for (int i = 0; i < 4; ++i) dst[tid + 256 * i] = ld_g(src + tid + 256 * i);
}

// gates g[16] laid out as g[gate*4 + cell]; i,f,g,o = PyTorch order
__device__ __forceinline__ void cellup(const float* g, float* c, float* hdst, int cell0, int tid) {
  if (tid < 4) {
    float gi = g[tid], gf = g[4 + tid], gg = g[8 + tid], go = g[12 + tid];
    float si = 1.f / (1.f + expf(-gi));
    float sf = 1.f / (1.f + expf(-gf));
    float so = 1.f / (1.f + expf(-go));
    float c2 = sf * c[tid] + si * tanhf(gg);
    c[tid] = c2;
    st_g(hdst + cell0 + tid, so * tanhf(c2));
  }
}

__global__ void __launch_bounds__(TPB) rf_kernel(
    const float* __restrict__ in_Wih0, const float* __restrict__ in_Whh0,
    const float* __restrict__ in_bih0, const float* __restrict__ in_bhh0,
    const float* __restrict__ in_Wih1, const float* __restrict__ in_Whh1,
    const float* __restrict__ in_bih1, const float* __restrict__ in_bhh1,
    const float* __restrict__ out_Wih0, const float* __restrict__ out_Whh0,
    const float* __restrict__ out_bih0, const float* __restrict__ out_bhh0,
    const float* __restrict__ out_Wih1, const float* __restrict__ out_Whh1,
    const float* __restrict__ out_bih1, const float* __restrict__ out_bhh1,
    const float* __restrict__ pr_Wih0, const float* __restrict__ pr_Whh0,
    const float* __restrict__ pr_bih0, const float* __restrict__ pr_bhh0,
    const float* __restrict__ pr_Wih1, const float* __restrict__ pr_Whh1,
    const float* __restrict__ pr_bih1, const float* __restrict__ pr_bhh1,
    const float* __restrict__ lin_W, const float* __restrict__ lin_b,
    const int* __restrict__ in_seq, const int* __restrict__ out_seq,
    float* __restrict__ out, float* __restrict__ ws)
{
  const int wg = blockIdx.x, tid = threadIdx.x;
  const int wave = tid >> 6, lane = tid & 63;
  const int cell0 = wg << 2;
  const int rbase = (wave << 10) + cell0;  // this wave's gate-row base

  // h double buffers (global, exchanged via relaxed atomics); parity = step & 1
  float* h0base = ws + 256;           // [2][1024]
  float* h1base = ws + 256 + 2 * HDIM; // [2][1024]

  __shared__ __align__(16) float xa[HDIM];
  __shared__ __align__(16) float xb[HDIM];
  __shared__ float gA[16], gB[16];
  __shared__ float c_lds[2][4];

  if (tid < 4) { c_lds[0][tid] = 0.f; c_lds[1][tid] = 0.f; }
  int lsense = 0, fail = 0;

  // bias caches (uniform across lanes of the wave)
  float b0_in[4], b1_in[4], b0_out[4], b1_out[4], b1_pr[4];
#pragma unroll
  for (int j = 0; j < 4; ++j) {
    b0_in[j]  = in_bih0[rbase + j]  + in_bhh0[rbase + j];
    b1_in[j]  = in_bih1[rbase + j]  + in_bhh1[rbase + j];
    b0_out[j] = out_bih0[rbase + j] + out_bhh0[rbase + j];
    b1_out[j] = out_bih1[rbase + j] + out_bhh1[rbase + j];
    b1_pr[j]  = pr_bih1[rbase + j]  + pr_bhh1[rbase + j];
  }
  const float lbias = lin_b[cell0 + wave];

  // ---------- Stage A: encoder layer0, step 0 ----------
  load_vec(xa, h0base + HDIM, tid);  // h0(-1) = 0 (parity 1 buffer, memset)
  __syncthreads();
  {
    int idx = in_seq[0];
    float s[4];
#pragma unroll
    for (int j = 0; j < 4; ++j) {
      float acc = dot1024(in_Whh0 + (size_t)(rbase + j) * HDIM, xa, lane);
      s[j] = wave_red64(acc) + b0_in[j] + in_Wih0[(size_t)(rbase + j) * 128 + idx];
    }
    if (lane == 0) {
#pragma unroll
      for (int j = 0; j < 4; ++j) gA[wave * 4 + j] = s[j];
    }
  }
  __syncthreads();
  cellup(gA, c_lds[0], h0base /*parity 0*/, cell0, tid);
  gbar(ws, wg, tid, lsense, fail);

  // ---------- Encoder loop: stage t = {layer1[t], layer0[t+1]} ----------
#pragma unroll 1
  for (int t = 0; t < 127; ++t) {
    load_vec(xa, h0base + (t & 1) * HDIM, tid);        // h0(t)
    load_vec(xb, h1base + ((t + 1) & 1) * HDIM, tid);  // h1(t-1)
    __syncthreads();

    const bool p1in = (t < 64);
    const float* Wih1 = p1in ? in_Wih1 : out_Wih1;
    const float* Whh1 = p1in ? in_Whh1 : out_Whh1;
    float s1[4];
#pragma unroll
    for (int j = 0; j < 4; ++j) {
      size_t r = (size_t)(rbase + j) * HDIM;
      float acc = dot1024(Wih1 + r, xa, lane) + dot1024(Whh1 + r, xb, lane);
      s1[j] = wave_red64(acc) + (p1in ? b1_in[j] : b1_out[j]);
    }

    const bool p0in = (t + 1 < 64);
    const float* Whh0 = p0in ? in_Whh0 : out_Whh0;
    const float* Wih0 = p0in ? in_Wih0 : out_Wih0;
    const int idx = p0in ? in_seq[t + 1] : out_seq[t + 1 - 64];
    float s0[4];
#pragma unroll
    for (int j = 0; j < 4; ++j) {
      float acc = dot1024(Whh0 + (size_t)(rbase + j) * HDIM, xa, lane);
      s0[j] = wave_red64(acc) + (p0in ? b0_in[j] : b0_out[j])
            + Wih0[(size_t)(rbase + j) * 128 + idx];
    }

    if (lane == 0) {
#pragma unroll
      for (int j = 0; j < 4; ++j) { gA[wave * 4 + j] = s1[j]; gB[wave * 4 + j] = s0[j]; }
    }
    __syncthreads();
    cellup(gA, c_lds[1], h1base + (t & 1) * HDIM, cell0, tid);         // h1(t)
    cellup(gB, c_lds[0], h0base + ((t + 1) & 1) * HDIM, cell0, tid);   // h0(t+1)
    gbar(ws, wg, tid, lsense, fail);
  }

  // ---------- Stage B: layer1[127] ----------
  load_vec(xa, h0base + HDIM, tid);  // h0(127), parity 1
  load_vec(xb, h1base, tid);         // h1(126), parity 0
  __syncthreads();
  {
    float s1[4];
#pragma unroll
    for (int j = 0; j < 4; ++j) {
      size_t r = (size_t)(rbase + j) * HDIM;
      float acc = dot1024(out_Wih1 + r, xa, lane) + dot1024(out_Whh1 + r, xb, lane);
      s1[j] = wave_red64(acc) + b1_out[j];
    }
    if (lane == 0) {
#pragma unroll
      for (int j = 0; j < 4; ++j) gA[wave * 4 + j] = s1[j];
    }
  }
  __syncthreads();
  cellup(gA, c_lds[1], h1base + HDIM, cell0, tid);  // h1(127), parity 1
  gbar(ws, wg, tid, lsense, fail);

  // ---------- Stage C+D: pre0 (constant decoder input) + decoder layer0 step 128 ----------
  load_vec(xa, h0base + HDIM, tid);  // h0(127)
  load_vec(xb, h1base + HDIM, tid);  // h1(127) = prev_h (constant decoder input)
  __syncthreads();
  float pre0[4];
  {
#pragma unroll
    for (int j = 0; j < 4; ++j) {
      size_t r = (size_t)(rbase + j) * HDIM;
      float acc = dot1024(pr_Wih0 + r, xb, lane);
      pre0[j] = wave_red64(acc) + pr_bih0[rbase + j] + pr_bhh0[rbase + j];
      float acc2 = dot1024(pr_Whh0 + r, xa, lane);
      float s0 = wave_red64(acc2) + pre0[j];
      if (lane == 0) gA[wave * 4 + j] = s0;
    }
  }
  __syncthreads();
  cellup(gA, c_lds[0], h0base /*h0(128), parity 0*/, cell0, tid);
  gbar(ws, wg, tid, lsense, fail);

  // ---------- Decoder loop: t=128..159, stage = {p1[t], p0[t+1], lin[t-1]} ----------
#pragma unroll 1
  for (int t = 128; t < 160; ++t) {
    load_vec(xa, h0base + (t & 1) * HDIM, tid);        // h0(t)
    load_vec(xb, h1base + ((t + 1) & 1) * HDIM, tid);  // h1(t-1)
    __syncthreads();

    float s1[4];
#pragma unroll
    for (int j = 0; j < 4; ++j) {
      size_t r = (size_t)(rbase + j) * HDIM;
      float acc = dot1024(pr_Wih1 + r, xa, lane) + dot1024(pr_Whh1 + r, xb, lane);
      s1[j] = wave_red64(acc) + b1_pr[j];
    }
    float s0[4] = {0.f, 0.f, 0.f, 0.f};
    if (t < 159) {
#pragma unroll
      for (int j = 0; j < 4; ++j) {
        float acc = dot1024(pr_Whh0 + (size_t)(rbase + j) * HDIM, xa, lane);
        s0[j] = wave_red64(acc) + pre0[j];
      }
    }
    if (t > 128) {  // output row for decode step t-1 (uses xb = h1(t-1))
      float acc = dot1024(lin_W + (size_t)(cell0 + wave) * HDIM, xb, lane);
      float v = wave_red64(acc) + lbias;
      if (lane == 0) out[(size_t)(t - 129) * 1024 + cell0 + wave] = v;
    }
    if (lane == 0) {
#pragma unroll
      for (int j = 0; j < 4; ++j) { gA[wave * 4 + j] = s1[j]; gB[wave * 4 + j] = s0[j]; }
    }
    __syncthreads();
    cellup(gA, c_lds[1], h1base + (t & 1) * HDIM, cell0, tid);  // h1(t)
    if (t < 159)
      cellup(gB, c_lds[0], h0base + ((t + 1) & 1) * HDIM, cell0, tid);  // h0(t+1)
    gbar(ws, wg, tid, lsense, fail);
  }

  // ---------- Stage F: final output row (decode step 31) ----------
  load_vec(xb, h1base + HDIM, tid);  // h1(159), parity 1
  __syncthreads();
  {
    float acc = dot1024(lin_W + (size_t)(cell0 + wave) * HDIM, xb, lane);
    float v = wave_red64(acc) + lbias;
    if (lane == 0) out[(size_t)31 * 1024 + cell0 + wave] = v;
  }
}

extern "C" void kernel_launch(void* const* d_in, const int* in_sizes, int n_in,
                              void* d_out, int out_size, void* d_ws, size_t ws_size,
                              hipStream_t stream) {
  (void)in_sizes; (void)n_in; (void)out_size; (void)ws_size;
  // zero barrier state + h double-buffers (ws is poisoned 0xAA by harness)
  hipMemsetAsync(d_ws, 0, 20480, stream);
  const float* F[26];
  for (int i = 0; i < 26; ++i) F[i] = (const float*)d_in[i];
  const int* iseq = (const int*)d_in[26];
  const int* oseq = (const int*)d_in[27];
  rf_kernel<<<dim3(NWG), dim3(TPB), 0, stream>>>(
      F[0], F[1], F[2], F[3], F[4], F[5], F[6], F[7],
      F[8], F[9], F[10], F[11], F[12], F[13], F[14], F[15],
      F[16], F[17], F[18], F[19], F[20], F[21], F[22], F[23],
      F[24], F[25], iseq, oseq, (float*)d_out, (float*)d_ws);
}

// Round 2
// 1254.056 us; speedup vs baseline: 1.6800x; 1.6800x over previous
//
#include <hip/hip_runtime.h>
#include <hip/hip_fp16.h>
#include <cmath>

#define HDIM 1024
#define TPB 256
#define M4 4194304ull                   // elements per 4096x1024 matrix
#define WS_WOFF 65536ull                // byte offset of fp16 weights in ws
#define CVT_TOTAL 42991616ull           // 10*M4 + 1024*1024
#define WS_NEEDED (WS_WOFF + CVT_TOTAL * 2ull)

typedef unsigned long long ulong64;

// ---- relaxed agent-scope atomics: coherence point, never invalidate caches ----
__device__ __forceinline__ float ld_g(const float* p) {
  return __hip_atomic_load(p, __ATOMIC_RELAXED, __HIP_MEMORY_SCOPE_AGENT);
}
__device__ __forceinline__ void st_g(float* p, float v) {
  __hip_atomic_store(p, v, __ATOMIC_RELAXED, __HIP_MEMORY_SCOPE_AGENT);
}
__device__ __forceinline__ ulong64 ld_g8(const ulong64* p) {
  return __hip_atomic_load(p, __ATOMIC_RELAXED, __HIP_MEMORY_SCOPE_AGENT);
}
__device__ __forceinline__ void st_h16(__half* p, __half v) {
  __hip_atomic_store((unsigned short*)p, __half_as_ushort(v),
                     __ATOMIC_RELAXED, __HIP_MEMORY_SCOPE_AGENT);
}

__device__ __forceinline__ float wave_red64(float v) {
#pragma unroll
  for (int off = 32; off; off >>= 1) v += __shfl_xor(v, off, 64);
  return v;
}

// 2-level sense-reversing grid barrier, relaxed atomics only.
// ib: group counters at ib[g*16] (g<NG), root at ib[NG*16], sense at ib[NG*16+16].
template <int NG>
__device__ __forceinline__ void gbar(float* ws, int wg, int tid, int& lsense, int& fail) {
  __syncthreads();
  if (tid == 0) {
    int* ib = (int*)ws;
    int s = lsense ^ 1;
    lsense = s;
    asm volatile("s_waitcnt vmcnt(0)" ::: "memory");
    int old = __hip_atomic_fetch_add(&ib[(wg & (NG - 1)) * 16], 1, __ATOMIC_RELAXED, __HIP_MEMORY_SCOPE_AGENT);
    bool set_sense = false;
    if (old == 31) {
      int r = __hip_atomic_fetch_add(&ib[NG * 16], 1, __ATOMIC_RELAXED, __HIP_MEMORY_SCOPE_AGENT);
      if (r == NG - 1) {
#pragma unroll
        for (int g = 0; g < NG; ++g)
          __hip_atomic_store(&ib[g * 16], 0, __ATOMIC_RELAXED, __HIP_MEMORY_SCOPE_AGENT);
        __hip_atomic_store(&ib[NG * 16], 0, __ATOMIC_RELAXED, __HIP_MEMORY_SCOPE_AGENT);
        asm volatile("s_waitcnt vmcnt(0)" ::: "memory");
        __hip_atomic_store(&ib[NG * 16 + 16], s, __ATOMIC_RELAXED, __HIP_MEMORY_SCOPE_AGENT);
        set_sense = true;
      }
    }
    if (!set_sense && !fail) {
      int spins = 0;
      while (__hip_atomic_load(&ib[NG * 16 + 16], __ATOMIC_RELAXED, __HIP_MEMORY_SCOPE_AGENT) != s) {
        if (++spins > (1 << 22)) { fail = 1; break; }
        __builtin_amdgcn_s_sleep(1);
      }
    }
    asm volatile("" ::: "memory");
  }
  __syncthreads();
}

// ================= fp16 path (512 WGs, 2 cells/WG) =================
#define NWG16 512
#define NG16 16

union F4H { float4 f; __half2 h[4]; };

__device__ __forceinline__ float h8fma(float4 wf, float4 vf, float acc) {
  F4H w, v; w.f = wf; v.f = vf;
#pragma unroll
  for (int i = 0; i < 4; ++i) {
    float2 a = __half22float2(w.h[i]);
    float2 b = __half22float2(v.h[i]);
    acc = fmaf(a.x, b.x, acc);
    acc = fmaf(a.y, b.y, acc);
  }
  return acc;
}

// gate layout g[gate*2 + cell]; cell update + fp16 h store
__device__ __forceinline__ void cellup2(const float* g, float* c, __half* hdst, int cell0, int tid) {
  if (tid < 2) {
    float gi = g[tid], gf = g[2 + tid], gg = g[4 + tid], go = g[6 + tid];
    float si = 1.f / (1.f + expf(-gi));
    float sf = 1.f / (1.f + expf(-gf));
    float so = 1.f / (1.f + expf(-go));
    float c2 = sf * c[tid] + si * tanhf(gg);
    c[tid] = c2;
    st_h16(hdst + cell0 + tid, __float2half(so * tanhf(c2)));
  }
}

__global__ void __launch_bounds__(TPB, 2) rf16_kernel(
    const float* __restrict__ in_Wih0, const float* __restrict__ in_bih0, const float* __restrict__ in_bhh0,
    const float* __restrict__ in_bih1, const float* __restrict__ in_bhh1,
    const float* __restrict__ out_Wih0, const float* __restrict__ out_bih0, const float* __restrict__ out_bhh0,
    const float* __restrict__ out_bih1, const float* __restrict__ out_bhh1,
    const float* __restrict__ pr_bih0, const float* __restrict__ pr_bhh0,
    const float* __restrict__ pr_bih1, const float* __restrict__ pr_bhh1,
    const float* __restrict__ lin_b,
    const int* __restrict__ in_seq, const int* __restrict__ out_seq,
    float* __restrict__ out, float* __restrict__ ws)
{
  const int wg = blockIdx.x, tid = threadIdx.x;
  const int wave = tid >> 6, lane = tid & 63;
  const int cell0 = wg << 1;
  const int rbase = (wave << 10) + cell0;

  const __half* wb = (const __half*)((const char*)ws + WS_WOFF);
  // matrices: 0 in_Wih1, 1 in_Whh1, 2 in_Whh0, 3 out_Wih1, 4 out_Whh1, 5 out_Whh0,
  //           6 pr_Wih1, 7 pr_Whh1, 8 pr_Whh0, 9 pr_Wih0, 10 lin_W
  __half* h0 = (__half*)((char*)ws + 2048);  // [2][1024]
  __half* h1 = h0 + 2 * HDIM;                // [2][1024]

  __shared__ __align__(16) ulong64 xa8[256];
  __shared__ __align__(16) ulong64 xb8[256];
  __shared__ float gA[8], gB[8];
  __shared__ float cL0[2], cL1[2];
  const float4* xa4 = (const float4*)xa8;
  const float4* xb4 = (const float4*)xb8;

  if (tid < 2) { cL0[tid] = 0.f; cL1[tid] = 0.f; }
  int lsense = 0, fail = 0;

  float b0_in[2], b1_in[2], b0_out[2], b1_out[2], b1_pr[2], prb0[2];
#pragma unroll
  for (int j = 0; j < 2; ++j) {
    b0_in[j]  = in_bih0[rbase + j]  + in_bhh0[rbase + j];
    b1_in[j]  = in_bih1[rbase + j]  + in_bhh1[rbase + j];
    b0_out[j] = out_bih0[rbase + j] + out_bhh0[rbase + j];
    b1_out[j] = out_bih1[rbase + j] + out_bhh1[rbase + j];
    b1_pr[j]  = pr_bih1[rbase + j]  + pr_bhh1[rbase + j];
    prb0[j]   = pr_bih0[rbase + j]  + pr_bhh0[rbase + j];
  }
  const float lbias = (wave < 2) ? lin_b[cell0 + wave] : 0.f;

  // ---------- Stage A: encoder layer0 step 0 (h=0 -> just bias + one-hot column) ----------
  {
    int idx = in_seq[0];
    if (lane == 0) {
#pragma unroll
      for (int j = 0; j < 2; ++j)
        gB[wave * 2 + j] = b0_in[j] + in_Wih0[(size_t)(rbase + j) * 128 + idx];
    }
    __syncthreads();
    cellup2(gB, cL0, h0 /*parity 0*/, cell0, tid);
    gbar<NG16>(ws, wg, tid, lsense, fail);
  }

  // ---------- Encoder loop: stage t = {layer1[t], layer0[t+1]} ----------
#pragma unroll 1
  for (int t = 0; t < 127; ++t) {
    const bool p1in = (t < 64);
    const bool p0in = (t + 1 < 64);
    const __half* W1i = wb + (p1in ? 0 : 3) * M4;
    const __half* W1h = wb + (p1in ? 1 : 4) * M4;
    const __half* W0h = wb + (p0in ? 2 : 5) * M4;
    const float* Wih0 = p0in ? in_Wih0 : out_Wih0;
    const int idx = p0in ? in_seq[t + 1] : out_seq[t - 63];

    float4 w[12];
    float wcol[2];
#pragma unroll
    for (int j = 0; j < 2; ++j) {
      const float4* r1i = (const float4*)(W1i + (size_t)(rbase + j) * HDIM);
      const float4* r1h = (const float4*)(W1h + (size_t)(rbase + j) * HDIM);
      const float4* r0h = (const float4*)(W0h + (size_t)(rbase + j) * HDIM);
      w[j * 6 + 0] = r1i[lane]; w[j * 6 + 1] = r1i[lane + 64];
      w[j * 6 + 2] = r1h[lane]; w[j * 6 + 3] = r1h[lane + 64];
      w[j * 6 + 4] = r0h[lane]; w[j * 6 + 5] = r0h[lane + 64];
      wcol[j] = Wih0[(size_t)(rbase + j) * 128 + idx];
    }
    xa8[tid] = ld_g8((const ulong64*)(h0 + (t & 1) * HDIM) + tid);
    xb8[tid] = ld_g8((const ulong64*)(h1 + ((t + 1) & 1) * HDIM) + tid);
    __syncthreads();

    float4 va0 = xa4[lane], va1 = xa4[lane + 64];
    float4 vb0 = xb4[lane], vb1 = xb4[lane + 64];
    float s1[2], s0[2];
#pragma unroll
    for (int j = 0; j < 2; ++j) {
      float a1 = h8fma(w[j * 6 + 0], va0, h8fma(w[j * 6 + 1], va1,
                 h8fma(w[j * 6 + 2], vb0, h8fma(w[j * 6 + 3], vb1, 0.f))));
      s1[j] = wave_red64(a1) + (p1in ? b1_in[j] : b1_out[j]);
      float a0 = h8fma(w[j * 6 + 4], va0, h8fma(w[j * 6 + 5], va1, 0.f));
      s0[j] = wave_red64(a0) + (p0in ? b0_in[j] : b0_out[j]) + wcol[j];
    }
    if (lane == 0) {
#pragma unroll
      for (int j = 0; j < 2; ++j) { gA[wave * 2 + j] = s1[j]; gB[wave * 2 + j] = s0[j]; }
    }
    __syncthreads();
    cellup2(gA, cL1, h1 + (t & 1) * HDIM, cell0, tid);
    cellup2(gB, cL0, h0 + ((t + 1) & 1) * HDIM, cell0, tid);
    gbar<NG16>(ws, wg, tid, lsense, fail);
  }

  // ---------- Stage B: layer1[127] ----------
  {
    const __half* W1i = wb + 3 * M4;
    const __half* W1h = wb + 4 * M4;
    float4 w[8];
#pragma unroll
    for (int j = 0; j < 2; ++j) {
      const float4* r1i = (const float4*)(W1i + (size_t)(rbase + j) * HDIM);
      const float4* r1h = (const float4*)(W1h + (size_t)(rbase + j) * HDIM);
      w[j * 4 + 0] = r1i[lane]; w[j * 4 + 1] = r1i[lane + 64];
      w[j * 4 + 2] = r1h[lane]; w[j * 4 + 3] = r1h[lane + 64];
    }
    xa8[tid] = ld_g8((const ulong64*)(h0 + HDIM) + tid);  // h0(127) parity 1
    xb8[tid] = ld_g8((const ulong64*)(h1) + tid);         // h1(126) parity 0
    __syncthreads();
    float4 va0 = xa4[lane], va1 = xa4[lane + 64];
    float4 vb0 = xb4[lane], vb1 = xb4[lane + 64];
#pragma unroll
    for (int j = 0; j < 2; ++j) {
      float a1 = h8fma(w[j * 4 + 0], va0, h8fma(w[j * 4 + 1], va1,
                 h8fma(w[j * 4 + 2], vb0, h8fma(w[j * 4 + 3], vb1, 0.f))));
      float s = wave_red64(a1) + b1_out[j];
      if (lane == 0) gA[wave * 2 + j] = s;
    }
    __syncthreads();
    cellup2(gA, cL1, h1 + HDIM, cell0, tid);  // h1(127) parity 1
    gbar<NG16>(ws, wg, tid, lsense, fail);
  }

  // ---------- Stage C+D: pre0 (constant decoder input) + decoder layer0 step 128 ----------
  float pre0[2];
  {
    const __half* Wp0i = wb + 9 * M4;  // pr_Wih0
    const __half* Wp0h = wb + 8 * M4;  // pr_Whh0
    float4 w[8];
#pragma unroll
    for (int j = 0; j < 2; ++j) {
      const float4* ri = (const float4*)(Wp0i + (size_t)(rbase + j) * HDIM);
      const float4* rh = (const float4*)(Wp0h + (size_t)(rbase + j) * HDIM);
      w[j * 4 + 0] = ri[lane]; w[j * 4 + 1] = ri[lane + 64];
      w[j * 4 + 2] = rh[lane]; w[j * 4 + 3] = rh[lane + 64];
    }
    xa8[tid] = ld_g8((const ulong64*)(h0 + HDIM) + tid);  // h0(127)
    xb8[tid] = ld_g8((const ulong64*)(h1 + HDIM) + tid);  // h1(127) = prev_h
    __syncthreads();
    float4 va0 = xa4[lane], va1 = xa4[lane + 64];
    float4 vb0 = xb4[lane], vb1 = xb4[lane + 64];
#pragma unroll
    for (int j = 0; j < 2; ++j) {
      float ai = h8fma(w[j * 4 + 0], vb0, h8fma(w[j * 4 + 1], vb1, 0.f));
      pre0[j] = wave_red64(ai) + prb0[j];
      float ah = h8fma(w[j * 4 + 2], va0, h8fma(w[j * 4 + 3], va1, 0.f));
      float s = wave_red64(ah) + pre0[j];
      if (lane == 0) gB[wave * 2 + j] = s;
    }
    __syncthreads();
    cellup2(gB, cL0, h0 /*h0(128) parity 0*/, cell0, tid);
    gbar<NG16>(ws, wg, tid, lsense, fail);
  }

  // ---------- Decoder loop: t=128..159, stage = {p1[t], p0[t+1], lin[t-1]} ----------
#pragma unroll 1
  for (int t = 128; t < 160; ++t) {
    const __half* W1i = wb + 6 * M4;
    const __half* W1h = wb + 7 * M4;
    const __half* W0h = wb + 8 * M4;
    float4 w1[8], w0[4], wl0, wl1;
#pragma unroll
    for (int j = 0; j < 2; ++j) {
      const float4* r1i = (const float4*)(W1i + (size_t)(rbase + j) * HDIM);
      const float4* r1h = (const float4*)(W1h + (size_t)(rbase + j) * HDIM);
      w1[j * 4 + 0] = r1i[lane]; w1[j * 4 + 1] = r1i[lane + 64];
      w1[j * 4 + 2] = r1h[lane]; w1[j * 4 + 3] = r1h[lane + 64];
    }
    if (t < 159) {
#pragma unroll
      for (int j = 0; j < 2; ++j) {
        const float4* r0h = (const float4*)(W0h + (size_t)(rbase + j) * HDIM);
        w0[j * 2 + 0] = r0h[lane]; w0[j * 2 + 1] = r0h[lane + 64];
      }
    }
    if (t > 128 && wave < 2) {
      const float4* rl = (const float4*)(wb + 10 * M4 + (size_t)(cell0 + wave) * HDIM);
      wl0 = rl[lane]; wl1 = rl[lane + 64];
    }
    xa8[tid] = ld_g8((const ulong64*)(h0 + (t & 1) * HDIM) + tid);
    xb8[tid] = ld_g8((const ulong64*)(h1 + ((t + 1) & 1) * HDIM) + tid);
    __syncthreads();

    float4 va0 = xa4[lane], va1 = xa4[lane + 64];
    float4 vb0 = xb4[lane], vb1 = xb4[lane + 64];
    float s1[2], s0[2] = {0.f, 0.f};
#pragma unroll
    for (int j = 0; j < 2; ++j) {
      float a1 = h8fma(w1[j * 4 + 0], va0, h8fma(w1[j * 4 + 1], va1,
                 h8fma(w1[j * 4 + 2], vb0, h8fma(w1[j * 4 + 3], vb1, 0.f))));
      s1[j] = wave_red64(a1) + b1_pr[j];
    }
    if (t < 159) {
#pragma unroll
      for (int j = 0; j < 2; ++j) {
        float a0 = h8fma(w0[j * 2 + 0], va0, h8fma(w0[j * 2 + 1], va1, 0.f));
        s0[j] = wave_red64(a0) + pre0[j];
      }
    }
    if (t > 128 && wave < 2) {
      float al = h8fma(wl0, vb0, h8fma(wl1, vb1, 0.f));
      float v = wave_red64(al) + lbias;
      if (lane == 0) out[(size_t)(t - 129) * 1024 + cell0 + wave] = v;
    }
    if (lane == 0) {
#pragma unroll
      for (int j = 0; j < 2; ++j) { gA[wave * 2 + j] = s1[j]; gB[wave * 2 + j] = s0[j]; }
    }
    __syncthreads();
    cellup2(gA, cL1, h1 + (t & 1) * HDIM, cell0, tid);
    if (t < 159) cellup2(gB, cL0, h0 + ((t + 1) & 1) * HDIM, cell0, tid);
    gbar<NG16>(ws, wg, tid, lsense, fail);
  }

  // ---------- Stage F: final output row (decode step 31) ----------
  {
    float4 wl0, wl1;
    if (wave < 2) {
      const float4* rl = (const float4*)(wb + 10 * M4 + (size_t)(cell0 + wave) * HDIM);
      wl0 = rl[lane]; wl1 = rl[lane + 64];
    }
    xb8[tid] = ld_g8((const ulong64*)(h1 + HDIM) + tid);  // h1(159) parity 1
    __syncthreads();
    if (wave < 2) {
      float4 vb0 = xb4[lane], vb1 = xb4[lane + 64];
      float al = h8fma(wl0, vb0, h8fma(wl1, vb1, 0.f));
      float v = wave_red64(al) + lbias;
      if (lane == 0) out[(size_t)31 * 1024 + cell0 + wave] = v;
    }
  }
}

// ================= fp32 -> fp16 weight conversion =================
struct CvtArgs { const float* s[11]; };

__global__ void __launch_bounds__(256) cvt_kernel(CvtArgs a, __half* dst) {
  size_t i = ((size_t)blockIdx.x * 256 + threadIdx.x) * 8;
  if (i >= CVT_TOTAL) return;
  const float* sp;
  if (i < 10 * M4) sp = a.s[i >> 22] + (i & (M4 - 1));
  else sp = a.s[10] + (i - 10 * M4);
  float4 f0 = ((const float4*)sp)[0];
  float4 f1 = ((const float4*)sp)[1];
  __half2 o[4];
  o[0] = __float22half2_rn(make_float2(f0.x, f0.y));
  o[1] = __float22half2_rn(make_float2(f0.z, f0.w));
  o[2] = __float22half2_rn(make_float2(f1.x, f1.y));
  o[3] = __float22half2_rn(make_float2(f1.z, f1.w));
  *((float4*)(dst + i)) = *(float4*)o;
}

// ================= fp32 fallback (round-1 kernel, 256 WGs) =================
#define NWG32F 256

__device__ __forceinline__ float dot1024(const float* __restrict__ w,
                                         const float* __restrict__ x, int lane) {
  const float4* w4 = reinterpret_cast<const float4*>(w);
  const float4* x4 = reinterpret_cast<const float4*>(x);
  float a0 = 0.f, a1 = 0.f;
#pragma unroll
  for (int k = 0; k < 4; k += 2) {
    float4 wa = w4[lane + 64 * k];
    float4 va = x4[lane + 64 * k];
    float4 wbv = w4[lane + 64 * (k + 1)];
    float4 vb = x4[lane + 64 * (k + 1)];
    a0 = fmaf(wa.x, va.x, a0); a0 = fmaf(wa.y, va.y, a0);
    a0 = fmaf(wa.z, va.z, a0); a0 = fmaf(wa.w, va.w, a0);
    a1 = fmaf(wbv.x, vb.x, a1); a1 = fmaf(wbv.y, vb.y, a1);
    a1 = fmaf(wbv.z, vb.z, a1); a1 = fmaf(wbv.w, vb.w, a1);
  }
  return a0 + a1;
}

__device__ __forceinline__ void load_vecf(float* dst, const float* src, int tid) {
#pragma unroll
  for (int i = 0; i < 4; ++i) dst[tid + 256 * i] = ld_g(src + tid + 256 * i);
}

__device__ __forceinline__ void cellup4(const float* g, float* c, float* hdst, int cell0, int tid) {
  if (tid < 4) {
    float gi = g[tid], gf = g[4 + tid], gg = g[8 + tid], go = g[12 + tid];
    float si = 1.f / (1.f + expf(-gi));
    float sf = 1.f / (1.f + expf(-gf));
    float so = 1.f / (1.f + expf(-go));
    float c2 = sf * c[tid] + si * tanhf(gg);
    c[tid] = c2;
    st_g(hdst + cell0 + tid, so * tanhf(c2));
  }
}

__global__ void __launch_bounds__(TPB) rf_kernel_f32(
    const float* __restrict__ in_Wih0, const float* __restrict__ in_Whh0,
    const float* __restrict__ in_bih0, const float* __restrict__ in_bhh0,
    const float* __restrict__ in_Wih1, const float* __restrict__ in_Whh1,
    const float* __restrict__ in_bih1, const float* __restrict__ in_bhh1,
    const float* __restrict__ out_Wih0, const float* __restrict__ out_Whh0,
    const float* __restrict__ out_bih0, const float* __restrict__ out_bhh0,
    const float* __restrict__ out_Wih1, const float* __restrict__ out_Whh1,
    const float* __restrict__ out_bih1, const float* __restrict__ out_bhh1,
    const float* __restrict__ pr_Wih0, const float* __restrict__ pr_Whh0,
    const float* __restrict__ pr_bih0, const float* __restrict__ pr_bhh0,
    const float* __restrict__ pr_Wih1, const float* __restrict__ pr_Whh1,
    const float* __restrict__ pr_bih1, const float* __restrict__ pr_bhh1,
    const float* __restrict__ lin_W, const float* __restrict__ lin_b,
    const int* __restrict__ in_seq, const int* __restrict__ out_seq,
    float* __restrict__ out, float* __restrict__ ws)
{
  const int wg = blockIdx.x, tid = threadIdx.x;
  const int wave = tid >> 6, lane = tid & 63;
  const int cell0 = wg << 2;
  const int rbase = (wave << 10) + cell0;
  float* h0base = ws + 256;
  float* h1base = ws + 256 + 2 * HDIM;

  __shared__ __align__(16) float xa[HDIM];
  __shared__ __align__(16) float xb[HDIM];
  __shared__ float gA[16], gB[16];
  __shared__ float c_lds[2][4];

  if (tid < 4) { c_lds[0][tid] = 0.f; c_lds[1][tid] = 0.f; }
  int lsense = 0, fail = 0;

  float b0_in[4], b1_in[4], b0_out[4], b1_out[4], b1_pr[4];
#pragma unroll
  for (int j = 0; j < 4; ++j) {
    b0_in[j]  = in_bih0[rbase + j]  + in_bhh0[rbase + j];
    b1_in[j]  = in_bih1[rbase + j]  + in_bhh1[rbase + j];
    b0_out[j] = out_bih0[rbase + j] + out_bhh0[rbase + j];
    b1_out[j] = out_bih1[rbase + j] + out_bhh1[rbase + j];
    b1_pr[j]  = pr_bih1[rbase + j]  + pr_bhh1[rbase + j];
  }
  const float lbias = lin_b[cell0 + wave];

  load_vecf(xa, h0base + HDIM, tid);
  __syncthreads();
  {
    int idx = in_seq[0];
    float s[4];
#pragma unroll
    for (int j = 0; j < 4; ++j) {
      float acc = dot1024(in_Whh0 + (size_t)(rbase + j) * HDIM, xa, lane);
      s[j] = wave_red64(acc) + b0_in[j] + in_Wih0[(size_t)(rbase + j) * 128 + idx];
    }
    if (lane == 0) {
#pragma unroll
      for (int j = 0; j < 4; ++j) gA[wave * 4 + j] = s[j];
    }
  }
  __syncthreads();
  cellup4(gA, c_lds[0], h0base, cell0, tid);
  gbar<8>(ws, wg, tid, lsense, fail);

#pragma unroll 1
  for (int t = 0; t < 127; ++t) {
    load_vecf(xa, h0base + (t & 1) * HDIM, tid);
    load_vecf(xb, h1base + ((t + 1) & 1) * HDIM, tid);
    __syncthreads();
    const bool p1in = (t < 64);
    const float* Wih1 = p1in ? in_Wih1 : out_Wih1;
    const float* Whh1 = p1in ? in_Whh1 : out_Whh1;
    float s1[4];
#pragma unroll
    for (int j = 0; j < 4; ++j) {
      size_t r = (size_t)(rbase + j) * HDIM;
      float acc = dot1024(Wih1 + r, xa, lane) + dot1024(Whh1 + r, xb, lane);
      s1[j] = wave_red64(acc) + (p1in ? b1_in[j] : b1_out[j]);
    }
    const bool p0in = (t + 1 < 64);
    const float* Whh0 = p0in ? in_Whh0 : out_Whh0;
    const float* Wih0 = p0in ? in_Wih0 : out_Wih0;
    const int idx = p0in ? in_seq[t + 1] : out_seq[t + 1 - 64];
    float s0[4];
#pragma unroll
    for (int j = 0; j < 4; ++j) {
      float acc = dot1024(Whh0 + (size_t)(rbase + j) * HDIM, xa, lane);
      s0[j] = wave_red64(acc) + (p0in ? b0_in[j] : b0_out[j])
            + Wih0[(size_t)(rbase + j) * 128 + idx];
    }
    if (lane == 0) {
#pragma unroll
      for (int j = 0; j < 4; ++j) { gA[wave * 4 + j] = s1[j]; gB[wave * 4 + j] = s0[j]; }
    }
    __syncthreads();
    cellup4(gA, c_lds[1], h1base + (t & 1) * HDIM, cell0, tid);
    cellup4(gB, c_lds[0], h0base + ((t + 1) & 1) * HDIM, cell0, tid);
    gbar<8>(ws, wg, tid, lsense, fail);
  }

  load_vecf(xa, h0base + HDIM, tid);
  load_vecf(xb, h1base, tid);
  __syncthreads();
  {
    float s1[4];
#pragma unroll
    for (int j = 0; j < 4; ++j) {
      size_t r = (size_t)(rbase + j) * HDIM;
      float acc = dot1024(out_Wih1 + r, xa, lane) + dot1024(out_Whh1 + r, xb, lane);
      s1[j] = wave_red64(acc) + b1_out[j];
    }
    if (lane == 0) {
#pragma unroll
      for (int j = 0; j < 4; ++j) gA[wave * 4 + j] = s1[j];
    }
  }
  __syncthreads();
  cellup4(gA, c_lds[1], h1base + HDIM, cell0, tid);
  gbar<8>(ws, wg, tid, lsense, fail);

  load_vecf(xa, h0base + HDIM, tid);
  load_vecf(xb, h1base + HDIM, tid);
  __syncthreads();
  float pre0[4];
  {
#pragma unroll
    for (int j = 0; j < 4; ++j) {
      size_t r = (size_t)(rbase + j) * HDIM;
      float acc = dot1024(pr_Wih0 + r, xb, lane);
      pre0[j] = wave_red64(acc) + pr_bih0[rbase + j] + pr_bhh0[rbase + j];
      float acc2 = dot1024(pr_Whh0 + r, xa, lane);
      float s0 = wave_red64(acc2) + pre0[j];
      if (lane == 0) gA[wave * 4 + j] = s0;
    }
  }
  __syncthreads();
  cellup4(gA, c_lds[0], h0base, cell0, tid);
  gbar<8>(ws, wg, tid, lsense, fail);

#pragma unroll 1
  for (int t = 128; t < 160; ++t) {
    load_vecf(xa, h0base + (t & 1) * HDIM, tid);
    load_vecf(xb, h1base + ((t + 1) & 1) * HDIM, tid);
    __syncthreads();
    float s1[4];
#pragma unroll
    for (int j = 0; j < 4; ++j) {
      size_t r = (size_t)(rbase + j) * HDIM;
      float acc = dot1024(pr_Wih1 + r, xa, lane) + dot1024(pr_Whh1 + r, xb, lane);
      s1[j] = wave_red64(acc) + b1_pr[j];
    }
    float s0[4] = {0.f, 0.f, 0.f, 0.f};
    if (t < 159) {
#pragma unroll
      for (int j = 0; j < 4; ++j) {
        float acc = dot1024(pr_Whh0 + (size_t)(rbase + j) * HDIM, xa, lane);
        s0[j] = wave_red64(acc) + pre0[j];
      }
    }
    if (t > 128) {
      float acc = dot1024(lin_W + (size_t)(cell0 + wave) * HDIM, xb, lane);
      float v = wave_red64(acc) + lbias;
      if (lane == 0) out[(size_t)(t - 129) * 1024 + cell0 + wave] = v;
    }
    if (lane == 0) {
#pragma unroll
      for (int j = 0; j < 4; ++j) { gA[wave * 4 + j] = s1[j]; gB[wave * 4 + j] = s0[j]; }
    }
    __syncthreads();
    cellup4(gA, c_lds[1], h1base + (t & 1) * HDIM, cell0, tid);
    if (t < 159)
      cellup4(gB, c_lds[0], h0base + ((t + 1) & 1) * HDIM, cell0, tid);
    gbar<8>(ws, wg, tid, lsense, fail);
  }

  load_vecf(xb, h1base + HDIM, tid);
  __syncthreads();
  {
    float acc = dot1024(lin_W + (size_t)(cell0 + wave) * HDIM, xb, lane);
    float v = wave_red64(acc) + lbias;
    if (lane == 0) out[(size_t)31 * 1024 + cell0 + wave] = v;
  }
}

extern "C" void kernel_launch(void* const* d_in, const int* in_sizes, int n_in,
                              void* d_out, int out_size, void* d_ws, size_t ws_size,
                              hipStream_t stream) {
  (void)in_sizes; (void)n_in; (void)out_size;
  hipMemsetAsync(d_ws, 0, 20480, stream);
  const float* F[26];
  for (int i = 0; i < 26; ++i) F[i] = (const float*)d_in[i];
  const int* iseq = (const int*)d_in[26];
  const int* oseq = (const int*)d_in[27];

  if (ws_size >= WS_NEEDED) {
    CvtArgs ca;
    ca.s[0] = F[4];  ca.s[1] = F[5];  ca.s[2] = F[1];   // in_Wih1, in_Whh1, in_Whh0
    ca.s[3] = F[12]; ca.s[4] = F[13]; ca.s[5] = F[9];   // out_Wih1, out_Whh1, out_Whh0
    ca.s[6] = F[20]; ca.s[7] = F[21]; ca.s[8] = F[17];  // pr_Wih1, pr_Whh1, pr_Whh0
    ca.s[9] = F[16]; ca.s[10] = F[24];                  // pr_Wih0, lin_W
    __half* wdst = (__half*)((char*)d_ws + WS_WOFF);
    cvt_kernel<<<dim3((unsigned)(CVT_TOTAL / 8 / 256)), dim3(256), 0, stream>>>(ca, wdst);
    rf16_kernel<<<dim3(NWG16), dim3(TPB), 0, stream>>>(
        F[0], F[2], F[3], F[6], F[7],
        F[8], F[10], F[11], F[14], F[15],
        F[18], F[19], F[22], F[23],
        F[25], iseq, oseq, (float*)d_out, (float*)d_ws);
  } else {
    rf_kernel_f32<<<dim3(NWG32F), dim3(TPB), 0, stream>>>(
        F[0], F[1], F[2], F[3], F[4], F[5], F[6], F[7],
        F[8], F[9], F[10], F[11], F[12], F[13], F[14], F[15],
        F[16], F[17], F[18], F[19], F[20], F[21], F[22], F[23],
        F[24], F[25], iseq, oseq, (float*)d_out, (float*)d_ws);
  }
}

// Round 3
// 1013.147 us; speedup vs baseline: 2.0795x; 1.2378x over previous
//
#include <hip/hip_runtime.h>
#include <hip/hip_fp16.h>
#include <cmath>

#define HDIM 1024
#define TPB 512
#define NWG 256
#define M4 4194304ull                   // elements per 4096x1024 matrix
#define WS_WOFF 65536ull                // byte offset of fp16 weights in ws
#define CVT_TOTAL 42991616ull           // 10*M4 + 1024*1024
#define WS_NEEDED (WS_WOFF + CVT_TOTAL * 2ull)

typedef unsigned long long ulong64;
typedef _Float16 h2f __attribute__((ext_vector_type(2)));

// ---- relaxed agent-scope atomics: go to coherence point (L3), never invalidate caches ----
__device__ __forceinline__ ulong64 ld_g8(const ulong64* p) {
  return __hip_atomic_load(p, __ATOMIC_RELAXED, __HIP_MEMORY_SCOPE_AGENT);
}
__device__ __forceinline__ void st_h16(__half* p, __half v) {
  __hip_atomic_store((unsigned short*)p, __half_as_ushort(v),
                     __ATOMIC_RELAXED, __HIP_MEMORY_SCOPE_AGENT);
}
__device__ __forceinline__ void st_gi(int* p, int v) {
  __hip_atomic_store(p, v, __ATOMIC_RELAXED, __HIP_MEMORY_SCOPE_AGENT);
}

__device__ __forceinline__ float sigm(float x) { return 1.f / (1.f + __expf(-x)); }
__device__ __forceinline__ float tanh_f(float x) {
  float e = __expf(2.f * x);
  return 1.f - 2.f / (e + 1.f);
}

// dot of 8 packed halves (one float4) against 8 halves, fp32 accumulate
__device__ __forceinline__ float f4dot(float4 wf, float4 xf, float acc) {
  union { float4 f; h2f h[4]; } w, x;
  w.f = wf; x.f = xf;
#pragma unroll
  for (int i = 0; i < 4; ++i) {
#if __has_builtin(__builtin_amdgcn_fdot2)
    acc = __builtin_amdgcn_fdot2(w.h[i], x.h[i], acc, false);
#else
    acc = fmaf((float)w.h[i].x, (float)x.h[i].x, acc);
    acc = fmaf((float)w.h[i].y, (float)x.h[i].y, acc);
#endif
  }
  return acc;
}

// ================= persistent LSTM kernel =================
// 256 WGs x 512 threads. WG owns 4 cells. Wave w<4: layer1 of cell (wg*4+w);
// wave w>=4: layer0 of cell (wg*4+w-4) (+ decoder linear row). Within a wave,
// 16-lane group g computes gate g (PyTorch order i,f,g,o = rows g*1024+cell).
__global__ void __launch_bounds__(TPB, 2) rf16_kernel(
    const float* __restrict__ in_Wih0, const float* __restrict__ in_bih0, const float* __restrict__ in_bhh0,
    const float* __restrict__ in_bih1, const float* __restrict__ in_bhh1,
    const float* __restrict__ out_Wih0, const float* __restrict__ out_bih0, const float* __restrict__ out_bhh0,
    const float* __restrict__ out_bih1, const float* __restrict__ out_bhh1,
    const float* __restrict__ pr_bih0, const float* __restrict__ pr_bhh0,
    const float* __restrict__ pr_bih1, const float* __restrict__ pr_bhh1,
    const float* __restrict__ lin_b,
    const int* __restrict__ in_seq, const int* __restrict__ out_seq,
    float* __restrict__ out, float* __restrict__ ws)
{
  const int tid = threadIdx.x, wg = blockIdx.x;
  const int wv = tid >> 6, lane = tid & 63;
  const int grp = lane >> 4, gl = lane & 15;
  const int cell = (wg << 2) + (wv & 3);
  const bool isL1 = wv < 4;
  const int rowi = (grp << 10) + cell;           // my gate-row in 4096-row matrices

  const __half* wb = (const __half*)((const char*)ws + WS_WOFF);
  // fp16 matrices: 0 in_Wih1, 1 in_Whh1, 2 in_Whh0, 3 out_Wih1, 4 out_Whh1,
  //                5 out_Whh0, 6 pr_Wih1, 7 pr_Whh1, 8 pr_Whh0, 9 pr_Wih0, 10 lin_W
  __half* h0 = (__half*)((char*)ws + 4096);      // [2][1024] fp16, parity-double-buffered
  __half* h1 = h0 + 2 * HDIM;
  int* flags = (int*)ws;                          // [256] per-WG epoch flags

  __shared__ __align__(16) ulong64 xa8[256], xb8[256];
  const __half* xa = (const __half*)xa8;
  const __half* xb = (const __half*)xb8;

  float c_reg = 0.f, pre0v = 0.f, lbias = 0.f;
  float bA, bB, bC;                               // per-phase combined bias of my gate row
  if (isL1) {
    bA = in_bih1[rowi] + in_bhh1[rowi];
    bB = out_bih1[rowi] + out_bhh1[rowi];
    bC = pr_bih1[rowi] + pr_bhh1[rowi];
  } else {
    bA = in_bih0[rowi] + in_bhh0[rowi];
    bB = out_bih0[rowi] + out_bhh0[rowi];
    bC = pr_bih0[rowi] + pr_bhh0[rowi];
    lbias = lin_b[cell];
  }

  int stage = 0, fail = 0;
  float4 wreg[16];

  // --- lambdas ---
  auto preload8 = [&](const __half* wrow, int base) {
    const float4* w4 = (const float4*)wrow;
#pragma unroll
    for (int j = 0; j < 8; ++j) wreg[base + j] = w4[j * 16 + gl];
  };
  auto dotx = [&](int base, const __half* x, float acc) {
#pragma unroll
    for (int j = 0; j < 8; ++j)
      acc = f4dot(wreg[base + j], *(const float4*)(x + (j * 16 + gl) * 8), acc);
    return acc;
  };
  auto red16 = [&](float v) {
#pragma unroll
    for (int o = 1; o < 16; o <<= 1) v += __shfl_xor(v, o, 64);
    return v;
  };
  auto wred64 = [&](float v) {
#pragma unroll
    for (int o = 1; o < 64; o <<= 1) v += __shfl_xor(v, o, 64);
    return v;
  };
  auto stage_h = [&](const __half* a, const __half* b) {
    if (tid < 256) xa8[tid] = ld_g8((const ulong64*)a + tid);
    else           xb8[tid - 256] = ld_g8((const ulong64*)b + (tid - 256));
    __syncthreads();
  };
  auto cellup = [&](float v, float& c, __half* hdst) {
    float gi = __shfl(v, 0, 64), gf = __shfl(v, 16, 64);
    float gc = __shfl(v, 32, 64), go = __shfl(v, 48, 64);
    float c2 = sigm(gf) * c + sigm(gi) * tanh_f(gc);
    c = c2;
    if (lane == 0) st_h16(hdst + cell, __float2half(sigm(go) * tanh_f(c2)));
  };
  // flag barrier: store own epoch, poll all 256 flags >= epoch. No atomics,
  // no reset, no release hop. syncthreads before the store drains h-stores
  // (compiler emits s_waitcnt vmcnt(0) before s_barrier).
  auto gbar = [&]() {
    ++stage;
    __syncthreads();
    if (wv == 0) {
      if (lane == 0) st_gi(&flags[wg], stage);
      if (!fail) {
        const ulong64* f8 = (const ulong64*)flags;
        int spins = 0;
        for (;;) {
          ulong64 a = ld_g8(f8 + 2 * lane);
          ulong64 b = ld_g8(f8 + 2 * lane + 1);
          bool ok = ((int)a >= stage) && ((int)(a >> 32) >= stage) &&
                    ((int)b >= stage) && ((int)(b >> 32) >= stage);
          if (__all(ok)) break;
          if (++spins > (1 << 18)) { fail = 1; break; }  // anti-hang
          __builtin_amdgcn_s_sleep(1);
        }
      }
    }
    __syncthreads();
  };

  // ---------- Stage 1: encoder layer0, t=0 (h0(-1)=0 -> bias + one-hot col) ----------
  if (!isL1) {
    int idx = in_seq[0];
    float v = bA + in_Wih0[rowi * 128 + idx];
    cellup(v, c_reg, h0);                         // h0(0), parity 0
  }
  gbar();

  // ---------- Encoder loop: stage t = {layer1[t], layer0[t+1]}, t=0..126 ----------
#pragma unroll 1
  for (int t = 0; t < 127; ++t) {
    const bool p1in = t < 64, p0in = t < 63;
    float wcol = 0.f;
    if (isL1) {
      preload8(wb + (p1in ? 0 : 3) * M4 + rowi * 1024, 0);   // Wih1
      preload8(wb + (p1in ? 1 : 4) * M4 + rowi * 1024, 8);   // Whh1
    } else {
      preload8(wb + (p0in ? 2 : 5) * M4 + rowi * 1024, 0);   // Whh0
      int idx = p0in ? in_seq[t + 1] : out_seq[t - 63];
      wcol = (p0in ? in_Wih0 : out_Wih0)[rowi * 128 + idx];
    }
    stage_h(h0 + (t & 1) * HDIM, h1 + ((t + 1) & 1) * HDIM); // xa=h0(t), xb=h1(t-1)
    if (isL1) {
      float v = dotx(0, xa, 0.f);
      v = dotx(8, xb, v);
      v = red16(v) + (p1in ? bA : bB);
      cellup(v, c_reg, h1 + (t & 1) * HDIM);                 // h1(t)
    } else {
      float v = red16(dotx(0, xa, 0.f)) + (p0in ? bA : bB) + wcol;
      cellup(v, c_reg, h0 + ((t + 1) & 1) * HDIM);           // h0(t+1)
    }
    gbar();
  }

  // ---------- Stage: layer1[127] ----------
  if (isL1) {
    preload8(wb + 3 * M4 + rowi * 1024, 0);
    preload8(wb + 4 * M4 + rowi * 1024, 8);
  }
  stage_h(h0 + HDIM, h1);                          // xa=h0(127), xb=h1(126)
  if (isL1) {
    float v = dotx(0, xa, 0.f);
    v = dotx(8, xb, v);
    v = red16(v) + bB;
    cellup(v, c_reg, h1 + HDIM);                   // h1(127), parity 1
  }
  gbar();

  // ---------- Stage: pre0 (constant decoder input) + decoder layer0 step 128 ----------
  if (!isL1) {
    preload8(wb + 9 * M4 + rowi * 1024, 0);        // pr_Wih0
    preload8(wb + 8 * M4 + rowi * 1024, 8);        // pr_Whh0
  }
  stage_h(h0 + HDIM, h1 + HDIM);                   // xa=h0(127), xb=h1(127)=prev_h
  if (!isL1) {
    pre0v = red16(dotx(0, xb, 0.f)) + bC;          // my gate's constant input part
    float v = red16(dotx(8, xa, 0.f)) + pre0v;
    cellup(v, c_reg, h0);                          // h0(128), parity 0
  }
  gbar();

  // ---------- Decoder loop: t=128..159, stage = {p1[t], p0[t+1], lin[t-1]} ----------
#pragma unroll 1
  for (int t = 128; t < 160; ++t) {
    if (isL1) {
      preload8(wb + 6 * M4 + rowi * 1024, 0);      // pr_Wih1
      preload8(wb + 7 * M4 + rowi * 1024, 8);      // pr_Whh1
    } else {
      if (t < 159) preload8(wb + 8 * M4 + rowi * 1024, 0);   // pr_Whh0
      if (t > 128) {
        const float4* lw = (const float4*)(wb + 10 * M4 + (size_t)cell * 1024);
        wreg[8] = lw[lane * 2]; wreg[9] = lw[lane * 2 + 1];
      }
    }
    stage_h(h0 + (t & 1) * HDIM, h1 + ((t + 1) & 1) * HDIM); // xa=h0(t), xb=h1(t-1)
    if (isL1) {
      float v = dotx(0, xa, 0.f);
      v = dotx(8, xb, v);
      v = red16(v) + bC;
      cellup(v, c_reg, h1 + (t & 1) * HDIM);                 // h1(t)
    } else {
      if (t > 128) {                                         // out row for step t-129
        float a = f4dot(wreg[8], *(const float4*)(xb + lane * 16), 0.f);
        a = f4dot(wreg[9], *(const float4*)(xb + lane * 16 + 8), a);
        float r = wred64(a) + lbias;
        if (lane == 0) out[(size_t)(t - 129) * 1024 + cell] = r;
      }
      if (t < 159) {
        float v = red16(dotx(0, xa, 0.f)) + pre0v;
        cellup(v, c_reg, h0 + ((t + 1) & 1) * HDIM);         // h0(t+1)
      }
    }
    gbar();
  }

  // ---------- Final: output row for decode step 31 (h1(159)) ----------
  if (!isL1) {
    const float4* lw = (const float4*)(wb + 10 * M4 + (size_t)cell * 1024);
    wreg[0] = lw[lane * 2]; wreg[1] = lw[lane * 2 + 1];
  }
  stage_h(h0, h1 + HDIM);                          // xb=h1(159)
  if (!isL1) {
    float a = f4dot(wreg[0], *(const float4*)(xb + lane * 16), 0.f);
    a = f4dot(wreg[1], *(const float4*)(xb + lane * 16 + 8), a);
    float r = wred64(a) + lbias;
    if (lane == 0) out[(size_t)31 * 1024 + cell] = r;
  }
}

// ================= fp32 -> fp16 weight conversion =================
struct CvtArgs { const float* s[11]; };

__global__ void __launch_bounds__(256) cvt_kernel(CvtArgs a, __half* dst) {
  size_t i = ((size_t)blockIdx.x * 256 + threadIdx.x) * 8;
  if (i >= CVT_TOTAL) return;
  const float* sp;
  if (i < 10 * M4) sp = a.s[i >> 22] + (i & (M4 - 1));
  else sp = a.s[10] + (i - 10 * M4);
  float4 f0 = ((const float4*)sp)[0];
  float4 f1 = ((const float4*)sp)[1];
  __half2 o[4];
  o[0] = __float22half2_rn(make_float2(f0.x, f0.y));
  o[1] = __float22half2_rn(make_float2(f0.z, f0.w));
  o[2] = __float22half2_rn(make_float2(f1.x, f1.y));
  o[3] = __float22half2_rn(make_float2(f1.z, f1.w));
  *((float4*)(dst + i)) = *(float4*)o;
}

extern "C" void kernel_launch(void* const* d_in, const int* in_sizes, int n_in,
                              void* d_out, int out_size, void* d_ws, size_t ws_size,
                              hipStream_t stream) {
  (void)in_sizes; (void)n_in; (void)out_size;
  if (ws_size < WS_NEEDED) return;  // harness ws is known-large (round-2 verified)
  // zero flags + h double-buffers (ws poisoned 0xAA by harness)
  hipMemsetAsync(d_ws, 0, 65536, stream);
  const float* F[26];
  for (int i = 0; i < 26; ++i) F[i] = (const float*)d_in[i];
  const int* iseq = (const int*)d_in[26];
  const int* oseq = (const int*)d_in[27];

  CvtArgs ca;
  ca.s[0] = F[4];  ca.s[1] = F[5];  ca.s[2] = F[1];   // in_Wih1, in_Whh1, in_Whh0
  ca.s[3] = F[12]; ca.s[4] = F[13]; ca.s[5] = F[9];   // out_Wih1, out_Whh1, out_Whh0
  ca.s[6] = F[20]; ca.s[7] = F[21]; ca.s[8] = F[17];  // pr_Wih1, pr_Whh1, pr_Whh0
  ca.s[9] = F[16]; ca.s[10] = F[24];                  // pr_Wih0, lin_W
  __half* wdst = (__half*)((char*)d_ws + WS_WOFF);
  cvt_kernel<<<dim3((unsigned)(CVT_TOTAL / 8 / 256)), dim3(256), 0, stream>>>(ca, wdst);
  rf16_kernel<<<dim3(NWG), dim3(TPB), 0, stream>>>(
      F[0], F[2], F[3], F[6], F[7],
      F[8], F[10], F[11], F[14], F[15],
      F[18], F[19], F[22], F[23],
      F[25], iseq, oseq, (float*)d_out, (float*)d_ws);
}

// Round 5
// 787.033 us; speedup vs baseline: 2.6769x; 1.2873x over previous
//
#include <hip/hip_runtime.h>
#include <hip/hip_fp16.h>
#include <cmath>

#define HDIM 1024
#define TPB 512
#define NWG 256
#define M4 4194304ull                   // elements per 4096x1024 matrix
#define WS_WOFF 65536ull                // byte offset of fp16 weights in ws
#define CVT_TOTAL 42991616ull           // 10*M4 + 1024*1024
#define WS_NEEDED (WS_WOFF + CVT_TOTAL * 2ull)

typedef unsigned long long ulong64;
typedef unsigned int uint32;
typedef _Float16 h2f __attribute__((ext_vector_type(2)));

// ---- relaxed agent-scope atomics: go to coherence point (L3), never invalidate caches ----
__device__ __forceinline__ ulong64 ld_g8(const ulong64* p) {
  return __hip_atomic_load(p, __ATOMIC_RELAXED, __HIP_MEMORY_SCOPE_AGENT);
}
__device__ __forceinline__ void st_gu(uint32* p, uint32 v) {
  __hip_atomic_store(p, v, __ATOMIC_RELAXED, __HIP_MEMORY_SCOPE_AGENT);
}

__device__ __forceinline__ float sigm(float x) { return 1.f / (1.f + __expf(-x)); }
__device__ __forceinline__ float tanh_f(float x) {
  float e = __expf(2.f * x);
  return 1.f - 2.f / (e + 1.f);
}

// dot of 8 packed halves (one float4) against 8 halves, fp32 accumulate
__device__ __forceinline__ float f4dot(float4 wf, float4 xf, float acc) {
  union { float4 f; h2f h[4]; } w, x;
  w.f = wf; x.f = xf;
#pragma unroll
  for (int i = 0; i < 4; ++i) {
#if __has_builtin(__builtin_amdgcn_fdot2)
    acc = __builtin_amdgcn_fdot2(w.h[i], x.h[i], acc, false);
#else
    acc = fmaf((float)w.h[i].x, (float)x.h[i].x, acc);
    acc = fmaf((float)w.h[i].y, (float)x.h[i].y, acc);
#endif
  }
  return acc;
}

// ================= persistent dataflow LSTM kernel (no global barrier) =================
// 256 WGs x 512 threads. WG owns 4 cells. Wave wv<4: layer1 of cell wg*4+wv;
// wave wv>=4: layer0 of cell wg*4+wv-4 (+ decoder linear row). 16-lane group g
// computes gate g (PyTorch order i,f,g,o = rows g*1024+cell).
// h exchange: tagged words (tag<<16)|fp16 in 4 rotating global slots per stream.
// Per stage: wave 0 polls h0 stream, wave 1 polls h1 stream, both write packed
// halves to LDS; __syncthreads() publishes them to all waves (full ordering);
// compute waves then consume LDS and fire-and-forget tagged global stores.
__global__ void __launch_bounds__(TPB, 2) rf16_kernel(
    const float* __restrict__ in_Wih0, const float* __restrict__ in_bih0, const float* __restrict__ in_bhh0,
    const float* __restrict__ in_bih1, const float* __restrict__ in_bhh1,
    const float* __restrict__ out_Wih0, const float* __restrict__ out_bih0, const float* __restrict__ out_bhh0,
    const float* __restrict__ out_bih1, const float* __restrict__ out_bhh1,
    const float* __restrict__ pr_bih0, const float* __restrict__ pr_bhh0,
    const float* __restrict__ pr_bih1, const float* __restrict__ pr_bhh1,
    const float* __restrict__ lin_b,
    const int* __restrict__ in_seq, const int* __restrict__ out_seq,
    float* __restrict__ out, float* __restrict__ ws)
{
  const int tid = threadIdx.x, wg = blockIdx.x;
  const int wv = tid >> 6, lane = tid & 63;
  const int grp = lane >> 4, gl = lane & 15;
  const int cell = (wg << 2) + (wv & 3);
  const bool isL1 = wv < 4;
  const int rowi = (grp << 10) + cell;

  const __half* wb = (const __half*)((const char*)ws + WS_WOFF);
  // fp16 matrices: 0 in_Wih1, 1 in_Whh1, 2 in_Whh0, 3 out_Wih1, 4 out_Whh1,
  //                5 out_Whh0, 6 pr_Wih1, 7 pr_Whh1, 8 pr_Whh0, 9 pr_Wih0, 10 lin_W
  uint32* h0T = (uint32*)((char*)ws + 4096);            // 4 slots x 1024 tagged words
  uint32* h1T = (uint32*)((char*)ws + 4096 + 16384);

  __shared__ __align__(16) ulong64 xaP[2][128], xbP[2][128];  // packed h (2KB each)

  float c_reg = 0.f, pre0v = 0.f;
  float bA, bB, bC, lbias = 0.f;
  if (isL1) {
    bA = in_bih1[rowi] + in_bhh1[rowi];
    bB = out_bih1[rowi] + out_bhh1[rowi];
    bC = pr_bih1[rowi] + pr_bhh1[rowi];
  } else {
    bA = in_bih0[rowi] + in_bhh0[rowi];
    bB = out_bih0[rowi] + out_bhh0[rowi];
    bC = pr_bih0[rowi] + pr_bhh0[rowi];
    lbias = lin_b[cell];
  }

  int fail = 0;
  float4 wreg[16];
  float4 lw0, lw1;

  auto preload8 = [&](const __half* wrow, int base) {
    const float4* w4 = (const float4*)wrow;
#pragma unroll
    for (int j = 0; j < 8; ++j) wreg[base + j] = w4[j * 16 + gl];
  };
  auto dotx = [&](int base, const ulong64* xp, float acc) {
    const __half* x = (const __half*)xp;
#pragma unroll
    for (int j = 0; j < 8; ++j)
      acc = f4dot(wreg[base + j], *(const float4*)(x + (j * 16 + gl) * 8), acc);
    return acc;
  };
  auto red16 = [&](float v) {
#pragma unroll
    for (int o = 1; o < 16; o <<= 1) v += __shfl_xor(v, o, 64);
    return v;
  };
  auto wred64 = [&](float v) {
#pragma unroll
    for (int o = 1; o < 64; o <<= 1) v += __shfl_xor(v, o, 64);
    return v;
  };
  // poll one tagged 4KB vector (whole wave), write packed halves to LDS.
  // Publication to other waves happens at the per-stage __syncthreads().
  auto poll_pack = [&](const uint32* T, int tag, ulong64* dst) {
    if (fail) return;
    const ulong64* src = (const ulong64*)(T + ((tag & 3) << 10)) + (lane << 3);
    ulong64 d[8];
    int spins = 0;
    for (;;) {
      bool ok = true;
#pragma unroll
      for (int i = 0; i < 8; ++i) {
        d[i] = ld_g8(src + i);
        ok &= (((int)((d[i] >> 16) & 0xFFFF)) == tag) & (((int)(d[i] >> 48)) == tag);
      }
      if (__all(ok)) break;
      if (++spins > (1 << 18)) { fail = 1; return; }
      __builtin_amdgcn_s_sleep(1);
    }
    uint32 q[8];
#pragma unroll
    for (int i = 0; i < 8; ++i)
      q[i] = (uint32)(d[i] & 0xFFFF) | ((uint32)((d[i] >> 32) & 0xFFFF) << 16);
    ((uint4*)dst)[2 * lane]     = make_uint4(q[0], q[1], q[2], q[3]);
    ((uint4*)dst)[2 * lane + 1] = make_uint4(q[4], q[5], q[6], q[7]);
  };
  auto zero_pack = [&](ulong64* dst) {
    ((uint4*)dst)[2 * lane]     = make_uint4(0, 0, 0, 0);
    ((uint4*)dst)[2 * lane + 1] = make_uint4(0, 0, 0, 0);
  };
  // LSTM cell update from my gate pre-activation v; tagged fire-and-forget store
  auto produce = [&](float v, uint32* T, int tag) {
    float gi = __shfl(v, 0, 64), gf = __shfl(v, 16, 64);
    float gc = __shfl(v, 32, 64), go = __shfl(v, 48, 64);
    float c2 = sigm(gf) * c_reg + sigm(gi) * tanh_f(gc);
    c_reg = c2;
    if (lane == 0) {
      uint32 w = ((uint32)tag << 16) | (uint32)__half_as_ushort(__float2half(sigm(go) * tanh_f(c2)));
      st_gu(T + ((tag & 3) << 10) + cell, w);
    }
  };

  // ---------- Stage 1: L0 computes h0(0) (h=0, c=0 -> bias + one-hot column) ----------
  if (!isL1) {
    int idx = in_seq[0];
    float v = bA + in_Wih0[(size_t)rowi * 128 + idx];
    produce(v, h0T, 1);
  }

  // ---------- Encoder: phase-resident weights ----------
  if (isL1) {
    preload8(wb + 0 * M4 + (size_t)rowi * 1024, 0);   // in_Wih1
    preload8(wb + 1 * M4 + (size_t)rowi * 1024, 8);   // in_Whh1
  } else {
    preload8(wb + 2 * M4 + (size_t)rowi * 1024, 0);   // in_Whh0
  }

  // stages s=2..128: t=s-2; consume h0(t)[tag s-1], h1(t-1)[tag s-1];
  // produce h1(t)[tag s] (L1), h0(t+1)[tag s] (L0).
#pragma unroll 1
  for (int s = 2; s <= 128; ++s) {
    if (s == 65 && !isL1) preload8(wb + 5 * M4 + (size_t)rowi * 1024, 0);  // out_Whh0
    if (s == 66 && isL1) {
      preload8(wb + 3 * M4 + (size_t)rowi * 1024, 0);  // out_Wih1
      preload8(wb + 4 * M4 + (size_t)rowi * 1024, 8);  // out_Whh1
    }
    float wcol = 0.f;
    if (!isL1) {
      int idx = (s < 65) ? in_seq[s - 1] : out_seq[s - 65];
      wcol = ((s < 65) ? in_Wih0 : out_Wih0)[(size_t)rowi * 128 + idx];
    }
    if (wv == 0) poll_pack(h0T, s - 1, xaP[s & 1]);
    if (wv == 1) {
      if (s == 2) zero_pack(xbP[0]);
      else poll_pack(h1T, s - 1, xbP[s & 1]);
    }
    __syncthreads();
    if (isL1) {
      float v = dotx(0, xaP[s & 1], 0.f);
      v = dotx(8, xbP[s & 1], v);
      v = red16(v) + ((s < 66) ? bA : bB);
      produce(v, h1T, s);
    } else {
      float v = red16(dotx(0, xaP[s & 1], 0.f)) + ((s < 65) ? bA : bB) + wcol;
      produce(v, h0T, s);
    }
  }

  // ---------- Stage 129: layer1[127] (L0 compute idle) ----------
  if (wv == 0) poll_pack(h0T, 128, xaP[1]);
  if (wv == 1) poll_pack(h1T, 128, xbP[1]);
  __syncthreads();
  if (isL1) {
    float v = dotx(0, xaP[1], 0.f);
    v = dotx(8, xbP[1], v);
    v = red16(v) + bB;
    produce(v, h1T, 129);
  }

  // ---------- Stage 130: pre0 (constant decoder input) + decoder h0(128) (L1 idle) ----------
  if (!isL1) {
    preload8(wb + 9 * M4 + (size_t)rowi * 1024, 0);   // pr_Wih0
    preload8(wb + 8 * M4 + (size_t)rowi * 1024, 8);   // pr_Whh0
  }
  if (wv == 0) poll_pack(h0T, 128, xaP[0]);
  if (wv == 1) poll_pack(h1T, 129, xbP[0]);
  __syncthreads();
  if (!isL1) {
    pre0v = red16(dotx(0, xbP[0], 0.f)) + bC;          // pr_Wih0 . h1(127) + bias
    float v = red16(dotx(8, xaP[0], 0.f)) + pre0v;     // + pr_Whh0 . h0(127)
    produce(v, h0T, 130);
  }

  // ---------- Decoder-resident weights ----------
  if (isL1) {
    preload8(wb + 6 * M4 + (size_t)rowi * 1024, 0);   // pr_Wih1
    preload8(wb + 7 * M4 + (size_t)rowi * 1024, 8);   // pr_Whh1
  } else {
#pragma unroll
    for (int j = 0; j < 8; ++j) wreg[j] = wreg[8 + j];  // pr_Whh0 -> base 0
    const float4* lwp = (const float4*)(wb + 10 * M4 + (size_t)cell * 1024);
    lw0 = lwp[lane * 2]; lw1 = lwp[lane * 2 + 1];
  }

  // stages s=131..162: L1 consumes h0[tag s-1], h1[tag s==131?129:s-1]; produces h1[tag s].
  // L0 consumes h0[tag s-1] -> h0[tag s] (s<=161); linear row s-132 from xb (s>=132).
#pragma unroll 1
  for (int s = 131; s <= 162; ++s) {
    const int tb = (s == 131) ? 129 : s - 1;
    if (wv == 0) poll_pack(h0T, s - 1, xaP[s & 1]);
    if (wv == 1) poll_pack(h1T, tb, xbP[s & 1]);
    __syncthreads();
    if (isL1) {
      float v = dotx(0, xaP[s & 1], 0.f);
      v = dotx(8, xbP[s & 1], v);
      v = red16(v) + bC;
      produce(v, h1T, s);
    } else {
      if (s >= 132) {
        const __half* x = (const __half*)xbP[s & 1];
        float a = f4dot(lw0, *(const float4*)(x + lane * 16), 0.f);
        a = f4dot(lw1, *(const float4*)(x + lane * 16 + 8), a);
        float r = wred64(a) + lbias;
        if (lane == 0) out[(size_t)(s - 132) * 1024 + cell] = r;
      }
      if (s <= 161) {
        float v = red16(dotx(0, xaP[s & 1], 0.f)) + pre0v;
        produce(v, h0T, s);
      }
    }
  }

  // ---------- Stage 163: final linear row 31 from h1(159) [tag 162] ----------
  if (wv == 1) poll_pack(h1T, 162, xbP[1]);
  __syncthreads();
  if (!isL1) {
    const __half* x = (const __half*)xbP[1];
    float a = f4dot(lw0, *(const float4*)(x + lane * 16), 0.f);
    a = f4dot(lw1, *(const float4*)(x + lane * 16 + 8), a);
    float r = wred64(a) + lbias;
    if (lane == 0) out[(size_t)31 * 1024 + cell] = r;
  }
}

// ================= fp32 -> fp16 weight conversion =================
struct CvtArgs { const float* s[11]; };

__global__ void __launch_bounds__(256) cvt_kernel(CvtArgs a, __half* dst) {
  size_t i = ((size_t)blockIdx.x * 256 + threadIdx.x) * 8;
  if (i >= CVT_TOTAL) return;
  const float* sp;
  if (i < 10 * M4) sp = a.s[i >> 22] + (i & (M4 - 1));
  else sp = a.s[10] + (i - 10 * M4);
  float4 f0 = ((const float4*)sp)[0];
  float4 f1 = ((const float4*)sp)[1];
  __half2 o[4];
  o[0] = __float22half2_rn(make_float2(f0.x, f0.y));
  o[1] = __float22half2_rn(make_float2(f0.z, f0.w));
  o[2] = __float22half2_rn(make_float2(f1.x, f1.y));
  o[3] = __float22half2_rn(make_float2(f1.z, f1.w));
  *((float4*)(dst + i)) = *(float4*)o;
}

extern "C" void kernel_launch(void* const* d_in, const int* in_sizes, int n_in,
                              void* d_out, int out_size, void* d_ws, size_t ws_size,
                              hipStream_t stream) {
  (void)in_sizes; (void)n_in; (void)out_size;
  if (ws_size < WS_NEEDED) return;
  // zero tag slots (4 slots x 4KB x 2 streams at offset 4096) each launch/replay
  hipMemsetAsync(d_ws, 0, 40960, stream);
  const float* F[26];
  for (int i = 0; i < 26; ++i) F[i] = (const float*)d_in[i];
  const int* iseq = (const int*)d_in[26];
  const int* oseq = (const int*)d_in[27];

  CvtArgs ca;
  ca.s[0] = F[4];  ca.s[1] = F[5];  ca.s[2] = F[1];   // in_Wih1, in_Whh1, in_Whh0
  ca.s[3] = F[12]; ca.s[4] = F[13]; ca.s[5] = F[9];   // out_Wih1, out_Whh1, out_Whh0
  ca.s[6] = F[20]; ca.s[7] = F[21]; ca.s[8] = F[17];  // pr_Wih1, pr_Whh1, pr_Whh0
  ca.s[9] = F[16]; ca.s[10] = F[24];                  // pr_Wih0, lin_W
  __half* wdst = (__half*)((char*)d_ws + WS_WOFF);
  cvt_kernel<<<dim3((unsigned)(CVT_TOTAL / 8 / 256)), dim3(256), 0, stream>>>(ca, wdst);
  rf16_kernel<<<dim3(NWG), dim3(TPB), 0, stream>>>(
      F[0], F[2], F[3], F[6], F[7],
      F[8], F[10], F[11], F[14], F[15],
      F[18], F[19], F[22], F[23],
      F[25], iseq, oseq, (float*)d_out, (float*)d_ws);
}

// Round 8
// 630.109 us; speedup vs baseline: 3.3436x; 1.2490x over previous
//
#include <hip/hip_runtime.h>
#include <hip/hip_fp16.h>
#include <cmath>

#define HDIM 1024
#define TPB 512
#define NWG 256
#define M4 4194304ull                   // elements per 4096x1024 matrix
#define WS_WOFF 327680ull               // byte offset of fp16 weights in ws
#define CVT_TOTAL 42991616ull           // 10*M4 + 1024*1024
#define WS_NEEDED (WS_WOFF + CVT_TOTAL * 2ull)
// ws layout: [4096,20480) master h0 (4 slots x 4KB tagged words);
// [20480,36864) master h1; [36864,45056) flag mirrors: mirror m (0..7) at
// 36864+m*1024, inside: stream*512 + slot*64 + checker*4 (int tag values).

typedef unsigned long long ulong64;
typedef unsigned int uint32;
typedef _Float16 h2f __attribute__((ext_vector_type(2)));

// ---- agent-scope relaxed atomics: L3 coherence point, no cache invalidation ----
__device__ __forceinline__ ulong64 ld_g8(const ulong64* p) {
  return __hip_atomic_load(p, __ATOMIC_RELAXED, __HIP_MEMORY_SCOPE_AGENT);
}
__device__ __forceinline__ void st_gu(uint32* p, uint32 v) {
  __hip_atomic_store(p, v, __ATOMIC_RELAXED, __HIP_MEMORY_SCOPE_AGENT);
}
__device__ __forceinline__ void st_gi(int* p, int v) {
  __hip_atomic_store(p, v, __ATOMIC_RELAXED, __HIP_MEMORY_SCOPE_AGENT);
}

__device__ __forceinline__ float sigm(float x) { return 1.f / (1.f + __expf(-x)); }
__device__ __forceinline__ float tanh_f(float x) {
  float e = __expf(2.f * x);
  return 1.f - 2.f / (e + 1.f);
}

__device__ __forceinline__ float f4dot(float4 wf, float4 xf, float acc) {
  union { float4 f; h2f h[4]; } w, x;
  w.f = wf; x.f = xf;
#pragma unroll
  for (int i = 0; i < 4; ++i) {
#if __has_builtin(__builtin_amdgcn_fdot2)
    acc = __builtin_amdgcn_fdot2(w.h[i], x.h[i], acc, false);
#else
    acc = fmaf((float)w.h[i].x, (float)x.h[i].x, acc);
    acc = fmaf((float)w.h[i].y, (float)x.h[i].y, acc);
#endif
  }
  return acc;
}

// ================= persistent dataflow LSTM, checker/flag broadcast =================
// 256 WGs x 512 threads. WG owns 4 cells; waves 0-3 layer1, 4-7 layer0 (+linear).
// 16-lane group g computes gate g. h words: (tag<<16)|fp16, 4 rotating slots in L3.
// WGs 0-7 are "checkers": wave0/1 hot-sweep a 512B slice of the h0/h1 slot; on
// completion they fan the tag to 8 mirrored flag lines. All consumer waves poll
// one 32B flag line (their wg&7 mirror), then bulk-read the 4KB data once.
__global__ void __launch_bounds__(TPB, 2) rf16_kernel(
    const float* __restrict__ in_Wih0, const float* __restrict__ in_bih0, const float* __restrict__ in_bhh0,
    const float* __restrict__ in_bih1, const float* __restrict__ in_bhh1,
    const float* __restrict__ out_Wih0, const float* __restrict__ out_bih0, const float* __restrict__ out_bhh0,
    const float* __restrict__ out_bih1, const float* __restrict__ out_bhh1,
    const float* __restrict__ pr_bih0, const float* __restrict__ pr_bhh0,
    const float* __restrict__ pr_bih1, const float* __restrict__ pr_bhh1,
    const float* __restrict__ lin_b,
    const int* __restrict__ in_seq, const int* __restrict__ out_seq,
    float* __restrict__ out, float* __restrict__ ws)
{
  const int tid = threadIdx.x, wg = blockIdx.x;
  const int wv = tid >> 6, lane = tid & 63;
  const int grp = lane >> 4, gl = lane & 15;
  const int cell = (wg << 2) + (wv & 3);
  const bool isL1 = wv < 4;
  const int rowi = (grp << 10) + cell;
  const bool chkWG = (wg < 8);

  const __half* wb = (const __half*)((const char*)ws + WS_WOFF);
  // fp16 matrices: 0 in_Wih1, 1 in_Whh1, 2 in_Whh0, 3 out_Wih1, 4 out_Whh1,
  //                5 out_Whh0, 6 pr_Wih1, 7 pr_Whh1, 8 pr_Whh0, 9 pr_Wih0, 10 lin_W
  uint32* h0M = (uint32*)((char*)ws + 4096);
  uint32* h1M = (uint32*)((char*)ws + 20480);
  int* FL = (int*)((char*)ws + 36864);            // 8 mirrors x 1024B
  int* myFlag = FL + ((wg & 7) << 8);             // my mirror (ints)

  __shared__ __align__(16) ulong64 xaP[2][128], xbP[2][128];

  float c_reg = 0.f, pre0v = 0.f;
  float bA, bB, bC, lbias = 0.f;
  if (isL1) {
    bA = in_bih1[rowi] + in_bhh1[rowi];
    bB = out_bih1[rowi] + out_bhh1[rowi];
    bC = pr_bih1[rowi] + pr_bhh1[rowi];
  } else {
    bA = in_bih0[rowi] + in_bhh0[rowi];
    bB = out_bih0[rowi] + out_bhh0[rowi];
    bC = pr_bih0[rowi] + pr_bhh0[rowi];
    lbias = lin_b[cell];
  }

  int fail = 0;
  float4 wreg[16];
  float4 lw0, lw1;

  auto preload8 = [&](const __half* wrow, int base) {
    const float4* w4 = (const float4*)wrow;
#pragma unroll
    for (int j = 0; j < 8; ++j) wreg[base + j] = w4[j * 16 + gl];
  };
  auto dotx = [&](int base, const ulong64* xp, float acc) {
    const __half* x = (const __half*)xp;
#pragma unroll
    for (int j = 0; j < 8; ++j)
      acc = f4dot(wreg[base + j], *(const float4*)(x + (j * 16 + gl) * 8), acc);
    return acc;
  };
  auto red16 = [&](float v) {
#pragma unroll
    for (int o = 1; o < 16; o <<= 1) v += __shfl_xor(v, o, 64);
    return v;
  };
  auto wred64 = [&](float v) {
#pragma unroll
    for (int o = 1; o < 64; o <<= 1) v += __shfl_xor(v, o, 64);
    return v;
  };
  auto tags_ok = [&](const ulong64* d, int tag) {
    bool ok = true;
#pragma unroll
    for (int i = 0; i < 8; ++i)
      ok &= (((int)((d[i] >> 16) & 0xFFFF)) == tag) & (((int)(d[i] >> 48)) == tag);
    return ok;
  };
  auto pack_lds = [&](const ulong64* d, ulong64* dst) {
    uint32 q[8];
#pragma unroll
    for (int i = 0; i < 8; ++i)
      q[i] = (uint32)(d[i] & 0xFFFF) | ((uint32)((d[i] >> 32) & 0xFFFF) << 16);
    dst[4 * lane]     = (ulong64)q[0] | ((ulong64)q[1] << 32);
    dst[4 * lane + 1] = (ulong64)q[2] | ((ulong64)q[3] << 32);
    dst[4 * lane + 2] = (ulong64)q[4] | ((ulong64)q[5] << 32);
    dst[4 * lane + 3] = (ulong64)q[6] | ((ulong64)q[7] << 32);
  };
  // checker sweep + flag fanout + flag poll + single bulk data read
  auto fetch_pack = [&](const uint32* T, int stream, int tag, ulong64* dst) {
    if (fail) return;
    const int slot = tag & 3;
    if (chkWG) {
      // my 512B slice of this slot: lane reads one tagged 8B word
      const ulong64* sl = (const ulong64*)(T + (slot << 10)) + (wg << 6) + lane;
      int spins = 0;
      for (;;) {
        ulong64 w = ld_g8(sl);
        bool ok = (((int)((w >> 16) & 0xFFFF)) == tag) & (((int)(w >> 48)) == tag);
        if (__all(ok)) break;
        if (++spins > (1 << 20)) { fail = 1; break; }
      }
      if (!fail && lane < 8)   // fan my tag out to all 8 mirrors
        st_gi(FL + (lane << 8) + (stream << 7) + (slot << 4) + wg, tag);
    }
    // poll my mirror's 32B flag line (8 checker tags)
    {
      const ulong64* fp = (const ulong64*)(myFlag + (stream << 7) + (slot << 4));
      int spins = 0;
      for (;;) {
        ulong64 f0 = ld_g8(fp), f1 = ld_g8(fp + 1);
        ulong64 f2 = ld_g8(fp + 2), f3 = ld_g8(fp + 3);
        bool ok = (((int)f0) == tag) & (((int)(f0 >> 32)) == tag) &
                  (((int)f1) == tag) & (((int)(f1 >> 32)) == tag) &
                  (((int)f2) == tag) & (((int)(f2 >> 32)) == tag) &
                  (((int)f3) == tag) & (((int)(f3 >> 32)) == tag);
        if (ok) break;
        if (++spins > (1 << 20)) { fail = 1; return; }
        __builtin_amdgcn_s_sleep(1);
      }
    }
    // bulk data read (verified; passes on first iteration in steady state)
    const ulong64* src = (const ulong64*)(T + (slot << 10)) + (lane << 3);
    ulong64 d[8];
    int spins = 0;
    for (;;) {
#pragma unroll
      for (int i = 0; i < 8; ++i) d[i] = ld_g8(src + i);
      if (__all(tags_ok(d, tag))) break;
      if (++spins > (1 << 16)) { fail = 1; return; }
    }
    pack_lds(d, dst);
  };
  auto zero_pack = [&](ulong64* dst) {
#pragma unroll
    for (int i = 0; i < 4; ++i) dst[4 * lane + i] = 0ull;
  };
  // LSTM cell update; tagged fire-and-forget store to L3 master
  auto produce = [&](float v, uint32* T, int tag) {
    float gi = __shfl(v, 0, 64), gf = __shfl(v, 16, 64);
    float gc = __shfl(v, 32, 64), go = __shfl(v, 48, 64);
    float c2 = sigm(gf) * c_reg + sigm(gi) * tanh_f(gc);
    c_reg = c2;
    if (lane == 0) {
      uint32 w = ((uint32)tag << 16) | (uint32)__half_as_ushort(__float2half(sigm(go) * tanh_f(c2)));
      st_gu(T + ((tag & 3) << 10) + cell, w);
    }
  };

  // ---------- Stage 1: L0 computes h0(0) (h=0, c=0 -> bias + one-hot column) ----------
  if (!isL1) {
    int idx = in_seq[0];
    float v = bA + in_Wih0[(size_t)rowi * 128 + idx];
    produce(v, h0M, 1);
  }

  // ---------- Encoder phase-resident weights ----------
  if (isL1) {
    preload8(wb + 0 * M4 + (size_t)rowi * 1024, 0);   // in_Wih1
    preload8(wb + 1 * M4 + (size_t)rowi * 1024, 8);   // in_Whh1
  } else {
    preload8(wb + 2 * M4 + (size_t)rowi * 1024, 0);   // in_Whh0
  }

  // stages s=2..128: consume h0(t)[s-1], h1(t-1)[s-1]; produce h1(t)[s] / h0(t+1)[s]
#pragma unroll 1
  for (int s = 2; s <= 128; ++s) {
    if (s == 65 && !isL1) preload8(wb + 5 * M4 + (size_t)rowi * 1024, 0);  // out_Whh0
    if (s == 66 && isL1) {
      preload8(wb + 3 * M4 + (size_t)rowi * 1024, 0);  // out_Wih1
      preload8(wb + 4 * M4 + (size_t)rowi * 1024, 8);  // out_Whh1
    }
    float wcol = 0.f;
    if (!isL1) {
      int idx = (s < 65) ? in_seq[s - 1] : out_seq[s - 65];
      wcol = ((s < 65) ? in_Wih0 : out_Wih0)[(size_t)rowi * 128 + idx];
    }
    if (wv == 0) fetch_pack(h0M, 0, s - 1, xaP[s & 1]);
    if (wv == 1) {
      if (s == 2) zero_pack(xbP[0]);
      else fetch_pack(h1M, 1, s - 1, xbP[s & 1]);
    }
    __syncthreads();
    if (isL1) {
      float v = dotx(0, xaP[s & 1], 0.f);
      v = dotx(8, xbP[s & 1], v);
      v = red16(v) + ((s < 66) ? bA : bB);
      produce(v, h1M, s);
    } else {
      float v = red16(dotx(0, xaP[s & 1], 0.f)) + ((s < 65) ? bA : bB) + wcol;
      produce(v, h0M, s);
    }
  }

  // ---------- Stage 129: layer1[127] ----------
  if (wv == 0) fetch_pack(h0M, 0, 128, xaP[1]);
  if (wv == 1) fetch_pack(h1M, 1, 128, xbP[1]);
  __syncthreads();
  if (isL1) {
    float v = dotx(0, xaP[1], 0.f);
    v = dotx(8, xbP[1], v);
    v = red16(v) + bB;
    produce(v, h1M, 129);
  }

  // ---------- Stage 130: pre0 (constant decoder input) + decoder h0(128) ----------
  if (!isL1) {
    preload8(wb + 9 * M4 + (size_t)rowi * 1024, 0);   // pr_Wih0
    preload8(wb + 8 * M4 + (size_t)rowi * 1024, 8);   // pr_Whh0
  }
  if (wv == 0) fetch_pack(h0M, 0, 128, xaP[0]);
  if (wv == 1) fetch_pack(h1M, 1, 129, xbP[0]);
  __syncthreads();
  if (!isL1) {
    pre0v = red16(dotx(0, xbP[0], 0.f)) + bC;          // pr_Wih0 . h1(127) + bias
    float v = red16(dotx(8, xaP[0], 0.f)) + pre0v;     // + pr_Whh0 . h0(127)
    produce(v, h0M, 130);
  }

  // ---------- Decoder-resident weights ----------
  if (isL1) {
    preload8(wb + 6 * M4 + (size_t)rowi * 1024, 0);   // pr_Wih1
    preload8(wb + 7 * M4 + (size_t)rowi * 1024, 8);   // pr_Whh1
  } else {
#pragma unroll
    for (int j = 0; j < 8; ++j) wreg[j] = wreg[8 + j];  // pr_Whh0 -> base 0
    const float4* lwp = (const float4*)(wb + 10 * M4 + (size_t)cell * 1024);
    lw0 = lwp[lane * 2]; lw1 = lwp[lane * 2 + 1];
  }

  // stages s=131..162
#pragma unroll 1
  for (int s = 131; s <= 162; ++s) {
    const int tb = (s == 131) ? 129 : s - 1;
    if (wv == 0) fetch_pack(h0M, 0, s - 1, xaP[s & 1]);
    if (wv == 1) fetch_pack(h1M, 1, tb, xbP[s & 1]);
    __syncthreads();
    if (isL1) {
      float v = dotx(0, xaP[s & 1], 0.f);
      v = dotx(8, xbP[s & 1], v);
      v = red16(v) + bC;
      produce(v, h1M, s);
    } else {
      if (s >= 132) {
        const __half* x = (const __half*)xbP[s & 1];
        float a = f4dot(lw0, *(const float4*)(x + lane * 16), 0.f);
        a = f4dot(lw1, *(const float4*)(x + lane * 16 + 8), a);
        float r = wred64(a) + lbias;
        if (lane == 0) out[(size_t)(s - 132) * 1024 + cell] = r;
      }
      if (s <= 161) {
        float v = red16(dotx(0, xaP[s & 1], 0.f)) + pre0v;
        produce(v, h0M, s);
      }
    }
  }

  // ---------- Stage 163: final linear row 31 from h1(159) [tag 162] ----------
  if (wv == 1) fetch_pack(h1M, 1, 162, xbP[1]);
  __syncthreads();
  if (!isL1) {
    const __half* x = (const __half*)xbP[1];
    float a = f4dot(lw0, *(const float4*)(x + lane * 16), 0.f);
    a = f4dot(lw1, *(const float4*)(x + lane * 16 + 8), a);
    float r = wred64(a) + lbias;
    if (lane == 0) out[(size_t)31 * 1024 + cell] = r;
  }
}

// ================= fp32 -> fp16 weight conversion =================
struct CvtArgs { const float* s[11]; };

__global__ void __launch_bounds__(256) cvt_kernel(CvtArgs a, __half* dst) {
  size_t i = ((size_t)blockIdx.x * 256 + threadIdx.x) * 8;
  if (i >= CVT_TOTAL) return;
  const float* sp;
  if (i < 10 * M4) sp = a.s[i >> 22] + (i & (M4 - 1));
  else sp = a.s[10] + (i - 10 * M4);
  float4 f0 = ((const float4*)sp)[0];
  float4 f1 = ((const float4*)sp)[1];
  __half2 o[4];
  o[0] = __float22half2_rn(make_float2(f0.x, f0.y));
  o[1] = __float22half2_rn(make_float2(f0.z, f0.w));
  o[2] = __float22half2_rn(make_float2(f1.x, f1.y));
  o[3] = __float22half2_rn(make_float2(f1.z, f1.w));
  *((float4*)(dst + i)) = *(float4*)o;
}

extern "C" void kernel_launch(void* const* d_in, const int* in_sizes, int n_in,
                              void* d_out, int out_size, void* d_ws, size_t ws_size,
                              hipStream_t stream) {
  (void)in_sizes; (void)n_in; (void)out_size;
  if (ws_size < WS_NEEDED) return;
  // zero master slots + flag mirrors each launch/replay
  (void)hipMemsetAsync(d_ws, 0, 45056, stream);
  const float* F[26];
  for (int i = 0; i < 26; ++i) F[i] = (const float*)d_in[i];
  const int* iseq = (const int*)d_in[26];
  const int* oseq = (const int*)d_in[27];

  CvtArgs ca;
  ca.s[0] = F[4];  ca.s[1] = F[5];  ca.s[2] = F[1];   // in_Wih1, in_Whh1, in_Whh0
  ca.s[3] = F[12]; ca.s[4] = F[13]; ca.s[5] = F[9];   // out_Wih1, out_Whh1, out_Whh0
  ca.s[6] = F[20]; ca.s[7] = F[21]; ca.s[8] = F[17];  // pr_Wih1, pr_Whh1, pr_Whh0
  ca.s[9] = F[16]; ca.s[10] = F[24];                  // pr_Wih0, lin_W
  __half* wdst = (__half*)((char*)d_ws + WS_WOFF);
  cvt_kernel<<<dim3((unsigned)(CVT_TOTAL / 8 / 256)), dim3(256), 0, stream>>>(ca, wdst);
  rf16_kernel<<<dim3(NWG), dim3(TPB), 0, stream>>>(
      F[0], F[2], F[3], F[6], F[7],
      F[8], F[10], F[11], F[14], F[15],
      F[18], F[19], F[22], F[23],
      F[25], iseq, oseq, (float*)d_out, (float*)d_ws);
}